// Round 15
// baseline (251.679 us; speedup 1.0000x reference)
//
#include <hip/hip_runtime.h>
#include <math.h>

#define ROWS 18496          // bt*J*N = 64*17*17
#define SCALE 0.17677669529663687f  // 1/sqrt(32)

typedef unsigned short ushort_t;
typedef __attribute__((ext_vector_type(8))) short short8;
typedef __attribute__((ext_vector_type(4))) float f32x4;

__device__ __forceinline__ void fma4(float4& d, float s, const float4& v) {
    d.x = fmaf(s, v.x, d.x); d.y = fmaf(s, v.y, d.y);
    d.z = fmaf(s, v.z, d.z); d.w = fmaf(s, v.w, d.w);
}
__device__ __forceinline__ float dot4(const float4& a, const float4& b) {
    return a.x*b.x + a.y*b.y + a.z*b.z + a.w*b.w;
}

__device__ __forceinline__ ushort_t f2bf(float x) {
    union { float f; unsigned u; } v; v.f = x;
    unsigned r = v.u + 0x7fffu + ((v.u >> 16) & 1u);
    return (ushort_t)(r >> 16);
}
__device__ __forceinline__ float bf2f(ushort_t b) {
    union { unsigned u; float f; } v; v.u = ((unsigned)b) << 16; return v.f;
}

// packed f32-pair -> 2xbf16 (1 instr). Splits using it are self-correcting:
// lo = v - asfloat(hi) is computed from the ACTUAL hi, so hi+lo == v to f32
// precision regardless of the cvt rounding mode.
__device__ __forceinline__ unsigned cvtpk(float a, float b) {
    unsigned r;
    asm("v_cvt_pk_bf16_f32 %0, %1, %2" : "=v"(r) : "v"(a), "v"(b));
    return r;
}
__device__ __forceinline__ float uasf(unsigned u) {
    union { unsigned u; float f; } v; v.u = u; return v.f;
}

__device__ __forceinline__ void gl_lds16(const void* g, void* l) {
    __builtin_amdgcn_global_load_lds(
        (const __attribute__((address_space(1))) void*)g,
        (__attribute__((address_space(3))) void*)l, 16, 0, 0);
}

__device__ __forceinline__ void store_hilo(ushort_t* yhi, ushort_t* ylo,
                                           size_t off, const float4& a)
{
    unsigned h01 = cvtpk(a.x, a.y), h23 = cvtpk(a.z, a.w);
    unsigned l01 = cvtpk(a.x - uasf(h01 << 16), a.y - uasf(h01 & 0xffff0000u));
    unsigned l23 = cvtpk(a.z - uasf(h23 << 16), a.w - uasf(h23 & 0xffff0000u));
    *(uint2*)&yhi[off] = (uint2){h01, h23};
    *(uint2*)&ylo[off] = (uint2){l01, l23};
}

// ---------------- conversion kernel (Wqkv, Wp only — x fused into GEMM1) --
__global__ __launch_bounds__(256) void k_cvt_w(
    const float* __restrict__ W, ushort_t* __restrict__ bh, ushort_t* __restrict__ bl,
    const float* __restrict__ Wp, ushort_t* __restrict__ wph, ushort_t* __restrict__ wpl)
{
    if (blockIdx.x < 1280) {
        int o = blockIdx.x;          // 0..1279
        int kk = threadIdx.x;        // 0..255
        int col = (o & 255) * 5 + (o >> 8);
        float v = W[(size_t)kk * 1280 + col];
        ushort_t hh = f2bf(v);
        bh[(size_t)o * 256 + kk] = hh;
        bl[(size_t)o * 256 + kk] = f2bf(v - bf2f(hh));
    } else {
        // Wp (768x256 f32) -> transposed bf16 [n][k]
        int n = blockIdx.x - 1280;   // 0..255
        for (int k = threadIdx.x; k < 768; k += 256) {
            float v = Wp[(size_t)k * 256 + n];
            ushort_t h = f2bf(v);
            wph[(size_t)n * 768 + k] = h;
            wpl[(size_t)n * 768 + k] = f2bf(v - bf2f(h));
        }
    }
}

// ---------------- split-bf16 MFMA GEMM --------------------------------
// XCD-aware bijective block remap (round-8: -18 us on the two GEMMs).
// MODE==0: in-kernel f32->hi/lo A split with T14 issue-early prefetch
// (round-13): next K-step's A chunk loads issue after the staging barrier
// and hide under the MFMA phase.
template<int BM, int BN, int K, int MODE>
__global__ __launch_bounds__(256) void k_gemm(
    const float* __restrict__ Af,
    const ushort_t* __restrict__ Ahi, const ushort_t* __restrict__ Alo,
    const ushort_t* __restrict__ Bhi, const ushort_t* __restrict__ Blo,
    const float* __restrict__ aux,
    float* __restrict__ out)
{
    constexpr int MT = BM / 32;
    constexpr int NT = BN / 32;
    __shared__ __attribute__((aligned(16))) ushort_t sAh[BM * 32];
    __shared__ __attribute__((aligned(16))) ushort_t sAl[BM * 32];
    __shared__ __attribute__((aligned(16))) ushort_t sBh[BN * 32];
    __shared__ __attribute__((aligned(16))) ushort_t sBl[BN * 32];

    const int t = threadIdx.x;
    const int lane = t & 63;
    const int ln = lane & 15, quad = lane >> 4;
    const int wave = t >> 6;
    const int wm = wave >> 1, wn = wave & 1;

    const int nwg = (int)(gridDim.x * gridDim.y);
    int wgid = (int)(blockIdx.y * gridDim.x + blockIdx.x);
    int q = nwg >> 3, r = nwg & 7;
    int xcd = wgid & 7, i0 = wgid >> 3;
    int base = (xcd < r) ? xcd * (q + 1) : r * (q + 1) + (xcd - r) * q;
    int logical = base + i0;
    const int m0 = (logical / (int)gridDim.x) * BM;
    const int n0 = (logical % (int)gridDim.x) * BN;

    f32x4 acc[MT][NT];
#pragma unroll
    for (int i = 0; i < MT; ++i)
#pragma unroll
        for (int j = 0; j < NT; ++j) acc[i][j] = (f32x4){0.f, 0.f, 0.f, 0.f};

    // MODE 0: per-thread A-chunk prefetch registers (BM*2 == blockDim).
    float4 a0r, a1r, a2r, a3r;
    size_t a_base = 0;
    if (MODE == 0) {
        int row = t >> 1, kc8 = t & 1;
        int gr = m0 + row; if (gr > ROWS - 1) gr = ROWS - 1;
        a_base = (size_t)gr * K + kc8 * 16;
        const float* src = &Af[a_base];            // kb = 0
        a0r = *(const float4*)&src[0];
        a1r = *(const float4*)&src[4];
        a2r = *(const float4*)&src[8];
        a3r = *(const float4*)&src[12];
    }

    for (int kb = 0; kb < K; kb += 32) {
        __syncthreads();
        if (MODE == 0) {
            // write CURRENT chunk from regs (cvt at write time; no load wait)
            unsigned h0 = cvtpk(a0r.x, a0r.y), h1 = cvtpk(a0r.z, a0r.w);
            unsigned h2 = cvtpk(a1r.x, a1r.y), h3 = cvtpk(a1r.z, a1r.w);
            unsigned h4 = cvtpk(a2r.x, a2r.y), h5 = cvtpk(a2r.z, a2r.w);
            unsigned h6 = cvtpk(a3r.x, a3r.y), h7 = cvtpk(a3r.z, a3r.w);
            unsigned l0 = cvtpk(a0r.x - uasf(h0 << 16), a0r.y - uasf(h0 & 0xffff0000u));
            unsigned l1 = cvtpk(a0r.z - uasf(h1 << 16), a0r.w - uasf(h1 & 0xffff0000u));
            unsigned l2 = cvtpk(a1r.x - uasf(h2 << 16), a1r.y - uasf(h2 & 0xffff0000u));
            unsigned l3 = cvtpk(a1r.z - uasf(h3 << 16), a1r.w - uasf(h3 & 0xffff0000u));
            unsigned l4 = cvtpk(a2r.x - uasf(h4 << 16), a2r.y - uasf(h4 & 0xffff0000u));
            unsigned l5 = cvtpk(a2r.z - uasf(h5 << 16), a2r.w - uasf(h5 & 0xffff0000u));
            unsigned l6 = cvtpk(a3r.x - uasf(h6 << 16), a3r.y - uasf(h6 & 0xffff0000u));
            unsigned l7 = cvtpk(a3r.z - uasf(h7 << 16), a3r.w - uasf(h7 & 0xffff0000u));
            uint4* dh = (uint4*)((char*)sAh + (size_t)t * 32);
            uint4* dl = (uint4*)((char*)sAl + (size_t)t * 32);
            dh[0] = (uint4){h0, h1, h2, h3};
            dh[1] = (uint4){h4, h5, h6, h7};
            dl[0] = (uint4){l0, l1, l2, l3};
            dl[1] = (uint4){l4, l5, l6, l7};
        } else {
#pragma unroll
            for (int s = t; s < BM * 4; s += 256) {
                int row = s >> 2, kc = s & 3;
                int gr = m0 + row; if (gr > ROWS - 1) gr = ROWS - 1;
                size_t gb = ((size_t)gr * K + kb) * 2 + kc * 16;
                int lb = (s & ~63) * 16;
                gl_lds16((const char*)Ahi + gb, (char*)sAh + lb);
                gl_lds16((const char*)Alo + gb, (char*)sAl + lb);
            }
        }
#pragma unroll
        for (int s = t; s < BN * 4; s += 256) {
            int row = s >> 2, kc = s & 3;
            size_t gb = ((size_t)(n0 + row) * K + kb) * 2 + kc * 16;
            int lb = (s & ~63) * 16;
            gl_lds16((const char*)Bhi + gb, (char*)sBh + lb);
            gl_lds16((const char*)Blo + gb, (char*)sBl + lb);
        }
        __syncthreads();

        // issue NEXT K-step's A loads AFTER the barrier (latency hides under
        // the MFMA phase; the pre-barrier vmcnt(0) drain doesn't catch them).
        if (MODE == 0 && kb + 32 < K) {
            const float* src = &Af[a_base + kb + 32];
            a0r = *(const float4*)&src[0];
            a1r = *(const float4*)&src[4];
            a2r = *(const float4*)&src[8];
            a3r = *(const float4*)&src[12];
        }

        short8 ah[MT], al[MT], bh[NT], bl[NT];
#pragma unroll
        for (int i = 0; i < MT; ++i) {
            int off = (wm * (BM / 2) + i * 16 + ln) * 32 + quad * 8;
            ah[i] = *(const short8*)&sAh[off];
            al[i] = *(const short8*)&sAl[off];
        }
#pragma unroll
        for (int j = 0; j < NT; ++j) {
            int off = (wn * (BN / 2) + j * 16 + ln) * 32 + quad * 8;
            bh[j] = *(const short8*)&sBh[off];
            bl[j] = *(const short8*)&sBl[off];
        }
#pragma unroll
        for (int i = 0; i < MT; ++i)
#pragma unroll
            for (int j = 0; j < NT; ++j) {
                acc[i][j] = __builtin_amdgcn_mfma_f32_16x16x32_bf16(ah[i], bh[j], acc[i][j], 0, 0, 0);
                acc[i][j] = __builtin_amdgcn_mfma_f32_16x16x32_bf16(ah[i], bl[j], acc[i][j], 0, 0, 0);
                acc[i][j] = __builtin_amdgcn_mfma_f32_16x16x32_bf16(al[i], bh[j], acc[i][j], 0, 0, 0);
            }
    }

#pragma unroll
    for (int i = 0; i < MT; ++i) {
#pragma unroll
        for (int r2 = 0; r2 < 4; ++r2) {
            int gm = m0 + wm * (BM / 2) + i * 16 + quad * 4 + r2;
            if (gm >= ROWS) continue;
            if (MODE == 0) {
                int jn = gm % 289;
                const float* Mrow = &aux[(size_t)jn * 256];
#pragma unroll
                for (int j = 0; j < NT; ++j) {
                    int gn = n0 + wn * (BN / 2) + j * 16 + ln;
                    out[(size_t)gm * 1280 + gn] = acc[i][j][r2] * Mrow[gn & 255];
                }
            } else {
#pragma unroll
                for (int j = 0; j < NT; ++j) {
                    int gn = n0 + wn * (BN / 2) + j * 16 + ln;
                    out[(size_t)gm * 256 + gn] = acc[i][j][r2] + aux[gn];
                }
            }
        }
    }
}

// ---------------- fused attention: scores + softmaxes + all combines -----
// 512 threads (8 waves) per (b,h), grid 512. LDS 69.4 KB, (512,4) = 64 VGPR
// cap -> 2 blocks/CU.
// P1M: raw scores via MFMA. Both score sets are DIAGONAL 17x17 blocks of
// QK^T: att_v blocks are diagonal in natural row order p=j*17+n (rows share
// j); att_s blocks are diagonal in n-major order p=ln*17+gg (rows share n).
// Each block = one 16x16x32 MFMA tile (3-term split-bf16; A=q-frag and
// B=k-frag built in REGISTERS from global qkv5 — no LDS staging) covering
// rows/cols 0..15, plus a 33-entry f32 edge (row 16 / col 16) as scalar
// dots. 34 tiles x 3 = 102 MFMA + 1122 edge dots per block.
__global__ __launch_bounds__(512, 4) void k_att(
    const float* __restrict__ qkv5,
    const float* __restrict__ A_s, const float* __restrict__ A_v,
    const float* __restrict__ adjS, const float* __restrict__ adjV,
    ushort_t* __restrict__ yhi, ushort_t* __restrict__ ylo)
{
    __shared__ __attribute__((aligned(16))) float sm[17340];
    float* aS  = sm;            // 4913  [n][j][k]
    float* aV  = sm + 4913;     // 4913  [j][n][m]
    float* ebS = sm + 9826;     // 289
    float* ebV = sm + 10115;    // 289
    float* buf = sm + 10404;    // P3: vsv_t hi/lo (5376) | P4/P5: 289*24

    const int t  = threadIdx.x;
    const int bh = blockIdx.x;
    const int b  = bh >> 3, h = bh & 7;
    const size_t rowbase = (size_t)b * 289;

    // ---- P0: exp of symmetrized biases ----
    for (int idx = t; idx < 578; idx += 512) {
        int f = idx / 289, rem = idx % 289;
        int jj = rem / 17, kk = rem % 17;
        float bias;
        if (f == 0)
            bias = 0.5f * ((A_s[jj*17+kk] + adjS[jj*17+kk]) + (A_s[kk*17+jj] + adjS[kk*17+jj]));
        else
            bias = 0.5f * ((A_v[jj*17+kk] + adjV[jj*17+kk]) + (A_v[kk*17+jj] + adjV[kk*17+jj]));
        (f ? ebV : ebS)[rem] = expf(bias);
    }

    // ---- P1M: raw scores via MFMA (diagonal 17x17 blocks of QK^T) ----
    {
        const int lane = t & 63;
        const int ln = lane & 15, quad = lane >> 4;
        const int wave = t >> 6;                   // 0..7
        const float* qb = &qkv5[rowbase * 1280 + h * 32];
        const float* kb = &qkv5[rowbase * 1280 + 256 + h * 32];

        // main 16x16 tiles: rows/cols 0..15 of each 17x17 block
        for (int g = wave; g < 34; g += 8) {
            const bool isV = (g < 17);
            const int gg = isV ? g : g - 17;
            // row p for A (lane=row) and row p' for B (lane=col) share the
            // same index formula: V: gg*17+ln ; S: ln*17+gg
            const int rp = isV ? (gg * 17 + ln) : (ln * 17 + gg);
            const float* qsrc = &qb[(size_t)rp * 1280 + quad * 8];
            const float* ksrc = &kb[(size_t)rp * 1280 + quad * 8];
            float4 qv0 = *(const float4*)&qsrc[0];
            float4 qv1 = *(const float4*)&qsrc[4];
            float4 kv0 = *(const float4*)&ksrc[0];
            float4 kv1 = *(const float4*)&ksrc[4];
            union { short8 s; unsigned u[4]; } Ah, Al, Bh, Bl;
            Ah.u[0] = cvtpk(qv0.x, qv0.y); Ah.u[1] = cvtpk(qv0.z, qv0.w);
            Ah.u[2] = cvtpk(qv1.x, qv1.y); Ah.u[3] = cvtpk(qv1.z, qv1.w);
            Al.u[0] = cvtpk(qv0.x - uasf(Ah.u[0] << 16), qv0.y - uasf(Ah.u[0] & 0xffff0000u));
            Al.u[1] = cvtpk(qv0.z - uasf(Ah.u[1] << 16), qv0.w - uasf(Ah.u[1] & 0xffff0000u));
            Al.u[2] = cvtpk(qv1.x - uasf(Ah.u[2] << 16), qv1.y - uasf(Ah.u[2] & 0xffff0000u));
            Al.u[3] = cvtpk(qv1.z - uasf(Ah.u[3] << 16), qv1.w - uasf(Ah.u[3] & 0xffff0000u));
            Bh.u[0] = cvtpk(kv0.x, kv0.y); Bh.u[1] = cvtpk(kv0.z, kv0.w);
            Bh.u[2] = cvtpk(kv1.x, kv1.y); Bh.u[3] = cvtpk(kv1.z, kv1.w);
            Bl.u[0] = cvtpk(kv0.x - uasf(Bh.u[0] << 16), kv0.y - uasf(Bh.u[0] & 0xffff0000u));
            Bl.u[1] = cvtpk(kv0.z - uasf(Bh.u[1] << 16), kv0.w - uasf(Bh.u[1] & 0xffff0000u));
            Bl.u[2] = cvtpk(kv1.x - uasf(Bh.u[2] << 16), kv1.y - uasf(Bh.u[2] & 0xffff0000u));
            Bl.u[3] = cvtpk(kv1.z - uasf(Bh.u[3] << 16), kv1.w - uasf(Bh.u[3] & 0xffff0000u));
            f32x4 acc = (f32x4){0.f, 0.f, 0.f, 0.f};
            acc = __builtin_amdgcn_mfma_f32_16x16x32_bf16(Ah.s, Bh.s, acc, 0, 0, 0);
            acc = __builtin_amdgcn_mfma_f32_16x16x32_bf16(Ah.s, Bl.s, acc, 0, 0, 0);
            acc = __builtin_amdgcn_mfma_f32_16x16x32_bf16(Al.s, Bh.s, acc, 0, 0, 0);
            float* dst = (isV ? aV : aS) + gg * 289;
#pragma unroll
            for (int i = 0; i < 4; ++i) {
                int row = quad * 4 + i;           // 0..15
                dst[row * 17 + ln] = acc[i];      // col = ln (0..15)
            }
        }

        // edges: entries with row==16 or col==16 (33 per block), f32 dots
        for (int e = t; e < 1122; e += 512) {
            int g = e / 33, s = e % 33;
            const bool isV = (g < 17);
            const int gg = isV ? g : g - 17;
            int rr = (s < 17) ? 16 : (s - 17);
            int cc = (s < 17) ? s : 16;
            int qp2 = isV ? (gg * 17 + rr) : (rr * 17 + gg);
            int kp2 = isV ? (gg * 17 + cc) : (cc * 17 + gg);
            const float* qsrc = &qb[(size_t)qp2 * 1280];
            const float* ksrc = &kb[(size_t)kp2 * 1280];
            float acc = 0.f;
#pragma unroll
            for (int c8 = 0; c8 < 8; ++c8) {
                float4 qv = *(const float4*)&qsrc[c8 * 4];
                float4 kv = *(const float4*)&ksrc[c8 * 4];
                acc += dot4(qv, kv);
            }
            (isV ? aV : aS)[gg * 289 + rr * 17 + cc] = acc;
        }
    }
    __syncthreads();

    // ---- P2: in-place 3-pass softmax on all 578 rows (SCALE folded) ----
    for (int idx = t; idx < 578; idx += 512) {
        float* row = (idx < 289) ? &aS[idx * 17] : &aV[(idx - 289) * 17];
        float mx = row[0];
#pragma unroll
        for (int kk = 1; kk < 17; ++kk) mx = fmaxf(mx, row[kk]);
        float sum = 0.f;
#pragma unroll
        for (int kk = 0; kk < 17; ++kk) {
            float e = expf((row[kk] - mx) * SCALE);
            row[kk] = e; sum += e;
        }
        float inv = 1.f / sum;
#pragma unroll
        for (int kk = 0; kk < 17; ++kk) row[kk] *= inv;
    }
    // (no trailing sync: P3's staging sync orders P2 before consumers)

    // ---- P3: x_vsv via in-register-A split-bf16 MFMA ----
    {
        const int lane = t & 63;
        const int ln = lane & 15, quad = lane >> 4;
        const int wave = t >> 6;                  // 0..7
        ushort_t* vh = (ushort_t*)buf;            // [32][168] bf16 hi (pad 168)
        ushort_t* vl = vh + 32 * 168;             // lo

        f32x4 acc[3][2];
#pragma unroll
        for (int r = 0; r < 3; ++r) {
            acc[r][0] = (f32x4){0.f,0.f,0.f,0.f};
            acc[r][1] = (f32x4){0.f,0.f,0.f,0.f};
        }

        // per-lane row bases for the (up to) 3 row-tiles this wave owns
        int sbase[3], vbase[3];
#pragma unroll
        for (int r = 0; r < 3; ++r) {
            int p = (wave + 8 * r) * 16 + ln; if (p > 288) p = 288;
            int jj = (p * 61681) >> 20;           // p / 17
            int nn = p - jj * 17;
            sbase[r] = nn * 289 + jj * 17;        // aS row (n,j)
            vbase[r] = jj * 289 + nn * 17;        // aV row (j,n)
        }

        for (int khalf = 0; khalf < 2; ++khalf) {
            const int qbase = khalf * 160;
            const int V = khalf ? 129 : 160;      // valid q's this half
            __syncthreads();
            if (khalf == 1) {
                // bulk zero vh+vl (cols >=129 must be 0; reads reach col 159)
                uint4* z = (uint4*)vh;            // vh,vl contiguous: 1344 uint4
                for (int e = t; e < 1344; e += 512) z[e] = (uint4){0,0,0,0};
                __syncthreads();
            }
            // stage vsv transposed: vh/vl[c][ql], coalesced global reads
            for (int e = t; e < 32 * V; e += 512) {
                int ql = e >> 5, c = e & 31;
                float v = qkv5[(rowbase + qbase + ql) * 1280 + 1024 + h * 32 + c];
                unsigned hp = cvtpk(v, v);
                float lo = v - uasf(hp << 16);
                unsigned lp = cvtpk(lo, lo);
                vh[c * 168 + ql] = (ushort_t)hp;
                vl[c * 168 + ql] = (ushort_t)lp;
            }
            __syncthreads();
#pragma unroll
            for (int kstep = 0; kstep < 5; ++kstep) {
                const int q0 = qbase + kstep * 32 + quad * 8;
                const int lb = kstep * 32 + quad * 8;
#pragma unroll
                for (int r = 0; r < 3; ++r) {
                    if (r == 2 && wave >= 3) continue;   // rt>=19: no output
                    union { short8 s; unsigned u[4]; } A, L;
                    int qc0 = (q0 < 289) ? q0 : 288;     // clamp: in-bounds decode
                    int k17 = (qc0 * 61681) >> 20;       // qc0 / 17
                    int m17 = qc0 - k17 * 17;
                    float sv = aS[sbase[r] + k17];
#pragma unroll
                    for (int i2 = 0; i2 < 4; ++i2) {
                        float pv0 = sv * aV[vbase[r] + m17];
                        ++m17; if (m17 == 17) { m17 = 0; ++k17; sv = aS[sbase[r] + k17]; }
                        float pv1 = sv * aV[vbase[r] + m17];
                        ++m17; if (m17 == 17) { m17 = 0; ++k17; sv = aS[sbase[r] + k17]; }
                        if (khalf == 1) {                // khalf0: q <= 159 always valid
                            if (q0 + 2 * i2     >= 289) pv0 = 0.f;
                            if (q0 + 2 * i2 + 1 >= 289) pv1 = 0.f;
                        }
                        unsigned hp = cvtpk(pv0, pv1);
                        unsigned lp = cvtpk(pv0 - uasf(hp << 16),
                                            pv1 - uasf(hp & 0xffff0000u));
                        A.u[i2] = hp; L.u[i2] = lp;
                    }
#pragma unroll
                    for (int ct = 0; ct < 2; ++ct) {
                        short8 bh8 = *(const short8*)&vh[(ct * 16 + ln) * 168 + lb];
                        short8 bl8 = *(const short8*)&vl[(ct * 16 + ln) * 168 + lb];
                        acc[r][ct] = __builtin_amdgcn_mfma_f32_16x16x32_bf16(A.s, bh8, acc[r][ct], 0, 0, 0);
                        acc[r][ct] = __builtin_amdgcn_mfma_f32_16x16x32_bf16(A.s, bl8, acc[r][ct], 0, 0, 0);
                        acc[r][ct] = __builtin_amdgcn_mfma_f32_16x16x32_bf16(L.s, bh8, acc[r][ct], 0, 0, 0);
                    }
                }
            }
        }
        // store: D row = rt*16 + quad*4 + rr, col = ct*16 + ln
#pragma unroll
        for (int r = 0; r < 3; ++r) {
            int rt = wave + 8 * r;
            if (rt >= 19) continue;
#pragma unroll
            for (int ct = 0; ct < 2; ++ct) {
#pragma unroll
                for (int rr = 0; rr < 4; ++rr) {
                    int p = rt * 16 + quad * 4 + rr;
                    if (p > 288) continue;
                    float v = acc[r][ct][rr];
                    unsigned hp = cvtpk(v, v);
                    float lo = v - uasf(hp << 16);
                    unsigned lp = cvtpk(lo, lo);
                    size_t off = (rowbase + p) * 768 + h * 32 + ct * 16 + ln;
                    yhi[off] = (ushort_t)hp;
                    ylo[off] = (ushort_t)lp;
                }
            }
        }
    }

    // ---- P3.5: bias-normalize aS/aV IN PLACE (P3 was the last unbiased
    // consumer). row = row*eb / sum(row*eb). Barrier first: other waves may
    // still be reading unbiased values inside P3.
    __syncthreads();
    for (int idx = t; idx < 578; idx += 512) {
        float* row;
        const float* eb;
        if (idx < 289) { row = &aS[idx * 17]; eb = &ebS[(idx % 17) * 17]; }
        else { int i2 = idx - 289; row = &aV[i2 * 17]; eb = &ebV[(i2 % 17) * 17]; }
        float s = 0.f;
#pragma unroll
        for (int kk = 0; kk < 17; ++kk) { float wv = row[kk] * eb[kk]; row[kk] = wv; s += wv; }
        float inv = 1.f / s;
#pragma unroll
        for (int kk = 0; kk < 17; ++kk) row[kk] *= inv;
    }

    // ---- P4: x_vs -> y cols 256..511. c4-fastest map, buf stride 24 ----
    for (int ch = 0; ch < 2; ++ch) {
        __syncthreads();
        for (int idx = t; idx < 1156; idx += 512) {
            int p = idx >> 2, c = idx & 3;
            *(float4*)&buf[p * 24 + c * 4] =
                *(const float4*)&qkv5[(rowbase + p) * 1280 + 512 + h * 32 + ch * 16 + c * 4];
        }
        __syncthreads();
        for (int u = t; u < 1156; u += 512) {
            const int c4 = (u & 3) * 4, rest = u >> 2;   // rest 0..288
            const int n = rest % 17, j = rest / 17;
            const float* as = &aS[n * 289 + j * 17];     // pre-normalized biased
            float4 a0 = {0,0,0,0};
            for (int kk = 0; kk < 17; ++kk) {
                float4 v = *(const float4*)&buf[(kk * 17 + n) * 24 + c4];
                fma4(a0, as[kk], v);
            }
            store_hilo(yhi, ylo, (rowbase + j * 17 + n) * 768 + 256 + h * 32 + ch * 16 + c4, a0);
        }
    }

    // ---- P5: x_vv -> y cols 512..767. c4-fastest map, buf stride 24 ----
    for (int ch = 0; ch < 2; ++ch) {
        __syncthreads();
        for (int idx = t; idx < 1156; idx += 512) {
            int p = idx >> 2, c = idx & 3;
            *(float4*)&buf[p * 24 + c * 4] =
                *(const float4*)&qkv5[(rowbase + p) * 1280 + 768 + h * 32 + ch * 16 + c * 4];
        }
        __syncthreads();
        for (int u = t; u < 1156; u += 512) {
            const int c4 = (u & 3) * 4, rest = u >> 2;   // rest 0..288
            const int j = rest % 17, n = rest / 17;
            const float* av = &aV[j * 289 + n * 17];     // pre-normalized biased
            float4 a0 = {0,0,0,0};
            for (int mm = 0; mm < 17; ++mm) {
                float4 v = *(const float4*)&buf[(j * 17 + mm) * 24 + c4];
                fma4(a0, av[mm], v);
            }
            store_hilo(yhi, ylo, (rowbase + j * 17 + n) * 768 + 512 + h * 32 + ch * 16 + c4, a0);
        }
    }
}

extern "C" void kernel_launch(void* const* d_in, const int* in_sizes, int n_in,
                              void* d_out, int out_size, void* d_ws, size_t ws_size,
                              hipStream_t stream)
{
    const float* x    = (const float*)d_in[0];
    const float* A_s  = (const float*)d_in[1];
    const float* A_v  = (const float*)d_in[2];
    const float* Wqkv = (const float*)d_in[3];
    const float* Wp   = (const float*)d_in[4];
    const float* bp   = (const float*)d_in[5];
    const float* M    = (const float*)d_in[6];
    const float* adjS = (const float*)d_in[7];
    const float* adjV = (const float*)d_in[8];
    float* out = (float*)d_out;

    char* w = (char*)d_ws;
    float*    qkv5  = (float*)w;                          // 94.7 MB, dead after k_att
    ushort_t* wph   = (ushort_t*)(w + 94699520);          // dead gap after qkv5
    ushort_t* wpl   = (ushort_t*)(w + 94699520 + 393216);
    char* R = w + 134946816;
    ushort_t* wqh = (ushort_t*)(R + 18939904);
    ushort_t* wql = (ushort_t*)(R + 19595264);
    ushort_t* yhi = (ushort_t*)R;
    ushort_t* ylo = (ushort_t*)(R + 28422144);

    k_cvt_w<<<dim3(1536), 256, 0, stream>>>(Wqkv, wqh, wql, Wp, wph, wpl);
    k_gemm<128, 128, 256, 0><<<dim3(10, 145), 256, 0, stream>>>(x, nullptr, nullptr,
                                                                wqh, wql, M, qkv5);
    k_att<<<dim3(512), 512, 0, stream>>>(qkv5, A_s, A_v, adjS, adjV, yhi, ylo);
    k_gemm<128, 64, 768, 1><<<dim3(4, 145), 256, 0, stream>>>(nullptr, yhi, ylo,
                                                              wph, wpl, bp, out);
}

// Round 17
// 248.853 us; speedup vs baseline: 1.0114x; 1.0114x over previous
//
#include <hip/hip_runtime.h>
#include <math.h>

#define ROWS 18496          // bt*J*N = 64*17*17
#define SCALE 0.17677669529663687f  // 1/sqrt(32)

typedef unsigned short ushort_t;
typedef __attribute__((ext_vector_type(8))) short short8;
typedef __attribute__((ext_vector_type(4))) float f32x4;

__device__ __forceinline__ void fma4(float4& d, float s, const float4& v) {
    d.x = fmaf(s, v.x, d.x); d.y = fmaf(s, v.y, d.y);
    d.z = fmaf(s, v.z, d.z); d.w = fmaf(s, v.w, d.w);
}
__device__ __forceinline__ float dot4(const float4& a, const float4& b) {
    return a.x*b.x + a.y*b.y + a.z*b.z + a.w*b.w;
}

__device__ __forceinline__ ushort_t f2bf(float x) {
    union { float f; unsigned u; } v; v.f = x;
    unsigned r = v.u + 0x7fffu + ((v.u >> 16) & 1u);
    return (ushort_t)(r >> 16);
}
__device__ __forceinline__ float bf2f(ushort_t b) {
    union { unsigned u; float f; } v; v.u = ((unsigned)b) << 16; return v.f;
}

// packed f32-pair -> 2xbf16 (1 instr). Splits using it are self-correcting:
// lo = v - asfloat(hi) is computed from the ACTUAL hi, so hi+lo == v to f32
// precision regardless of the cvt rounding mode.
__device__ __forceinline__ unsigned cvtpk(float a, float b) {
    unsigned r;
    asm("v_cvt_pk_bf16_f32 %0, %1, %2" : "=v"(r) : "v"(a), "v"(b));
    return r;
}
__device__ __forceinline__ float uasf(unsigned u) {
    union { unsigned u; float f; } v; v.u = u; return v.f;
}

__device__ __forceinline__ void gl_lds16(const void* g, void* l) {
    __builtin_amdgcn_global_load_lds(
        (const __attribute__((address_space(1))) void*)g,
        (__attribute__((address_space(3))) void*)l, 16, 0, 0);
}

__device__ __forceinline__ void store_hilo(ushort_t* yhi, ushort_t* ylo,
                                           size_t off, const float4& a)
{
    unsigned h01 = cvtpk(a.x, a.y), h23 = cvtpk(a.z, a.w);
    unsigned l01 = cvtpk(a.x - uasf(h01 << 16), a.y - uasf(h01 & 0xffff0000u));
    unsigned l23 = cvtpk(a.z - uasf(h23 << 16), a.w - uasf(h23 & 0xffff0000u));
    *(uint2*)&yhi[off] = (uint2){h01, h23};
    *(uint2*)&ylo[off] = (uint2){l01, l23};
}

// ---------------- conversion kernel (Wqkv, Wp only — x fused into GEMM1) --
__global__ __launch_bounds__(256) void k_cvt_w(
    const float* __restrict__ W, ushort_t* __restrict__ bh, ushort_t* __restrict__ bl,
    const float* __restrict__ Wp, ushort_t* __restrict__ wph, ushort_t* __restrict__ wpl)
{
    if (blockIdx.x < 1280) {
        int o = blockIdx.x;          // 0..1279
        int kk = threadIdx.x;        // 0..255
        int col = (o & 255) * 5 + (o >> 8);
        float v = W[(size_t)kk * 1280 + col];
        ushort_t hh = f2bf(v);
        bh[(size_t)o * 256 + kk] = hh;
        bl[(size_t)o * 256 + kk] = f2bf(v - bf2f(hh));
    } else {
        // Wp (768x256 f32) -> transposed bf16 [n][k]
        int n = blockIdx.x - 1280;   // 0..255
        for (int k = threadIdx.x; k < 768; k += 256) {
            float v = Wp[(size_t)k * 256 + n];
            ushort_t h = f2bf(v);
            wph[(size_t)n * 768 + k] = h;
            wpl[(size_t)n * 768 + k] = f2bf(v - bf2f(h));
        }
    }
}

// ---------------- split-bf16 MFMA GEMM --------------------------------
// XCD-aware bijective block remap (round-8: -18 us on the two GEMMs).
// MODE==0: in-kernel f32->hi/lo A split with T14 issue-early prefetch
// (round-13): next K-step's A chunk loads issue after the staging barrier
// and hide under the MFMA phase.
template<int BM, int BN, int K, int MODE>
__global__ __launch_bounds__(256) void k_gemm(
    const float* __restrict__ Af,
    const ushort_t* __restrict__ Ahi, const ushort_t* __restrict__ Alo,
    const ushort_t* __restrict__ Bhi, const ushort_t* __restrict__ Blo,
    const float* __restrict__ aux,
    float* __restrict__ out)
{
    constexpr int MT = BM / 32;
    constexpr int NT = BN / 32;
    __shared__ __attribute__((aligned(16))) ushort_t sAh[BM * 32];
    __shared__ __attribute__((aligned(16))) ushort_t sAl[BM * 32];
    __shared__ __attribute__((aligned(16))) ushort_t sBh[BN * 32];
    __shared__ __attribute__((aligned(16))) ushort_t sBl[BN * 32];

    const int t = threadIdx.x;
    const int lane = t & 63;
    const int ln = lane & 15, quad = lane >> 4;
    const int wave = t >> 6;
    const int wm = wave >> 1, wn = wave & 1;

    const int nwg = (int)(gridDim.x * gridDim.y);
    int wgid = (int)(blockIdx.y * gridDim.x + blockIdx.x);
    int q = nwg >> 3, r = nwg & 7;
    int xcd = wgid & 7, i0 = wgid >> 3;
    int base = (xcd < r) ? xcd * (q + 1) : r * (q + 1) + (xcd - r) * q;
    int logical = base + i0;
    const int m0 = (logical / (int)gridDim.x) * BM;
    const int n0 = (logical % (int)gridDim.x) * BN;

    f32x4 acc[MT][NT];
#pragma unroll
    for (int i = 0; i < MT; ++i)
#pragma unroll
        for (int j = 0; j < NT; ++j) acc[i][j] = (f32x4){0.f, 0.f, 0.f, 0.f};

    // MODE 0: per-thread A-chunk prefetch registers (BM*2 == blockDim).
    float4 a0r, a1r, a2r, a3r;
    size_t a_base = 0;
    if (MODE == 0) {
        int row = t >> 1, kc8 = t & 1;
        int gr = m0 + row; if (gr > ROWS - 1) gr = ROWS - 1;
        a_base = (size_t)gr * K + kc8 * 16;
        const float* src = &Af[a_base];            // kb = 0
        a0r = *(const float4*)&src[0];
        a1r = *(const float4*)&src[4];
        a2r = *(const float4*)&src[8];
        a3r = *(const float4*)&src[12];
    }

    for (int kb = 0; kb < K; kb += 32) {
        __syncthreads();
        if (MODE == 0) {
            // write CURRENT chunk from regs (cvt at write time; no load wait)
            unsigned h0 = cvtpk(a0r.x, a0r.y), h1 = cvtpk(a0r.z, a0r.w);
            unsigned h2 = cvtpk(a1r.x, a1r.y), h3 = cvtpk(a1r.z, a1r.w);
            unsigned h4 = cvtpk(a2r.x, a2r.y), h5 = cvtpk(a2r.z, a2r.w);
            unsigned h6 = cvtpk(a3r.x, a3r.y), h7 = cvtpk(a3r.z, a3r.w);
            unsigned l0 = cvtpk(a0r.x - uasf(h0 << 16), a0r.y - uasf(h0 & 0xffff0000u));
            unsigned l1 = cvtpk(a0r.z - uasf(h1 << 16), a0r.w - uasf(h1 & 0xffff0000u));
            unsigned l2 = cvtpk(a1r.x - uasf(h2 << 16), a1r.y - uasf(h2 & 0xffff0000u));
            unsigned l3 = cvtpk(a1r.z - uasf(h3 << 16), a1r.w - uasf(h3 & 0xffff0000u));
            unsigned l4 = cvtpk(a2r.x - uasf(h4 << 16), a2r.y - uasf(h4 & 0xffff0000u));
            unsigned l5 = cvtpk(a2r.z - uasf(h5 << 16), a2r.w - uasf(h5 & 0xffff0000u));
            unsigned l6 = cvtpk(a3r.x - uasf(h6 << 16), a3r.y - uasf(h6 & 0xffff0000u));
            unsigned l7 = cvtpk(a3r.z - uasf(h7 << 16), a3r.w - uasf(h7 & 0xffff0000u));
            uint4* dh = (uint4*)((char*)sAh + (size_t)t * 32);
            uint4* dl = (uint4*)((char*)sAl + (size_t)t * 32);
            dh[0] = (uint4){h0, h1, h2, h3};
            dh[1] = (uint4){h4, h5, h6, h7};
            dl[0] = (uint4){l0, l1, l2, l3};
            dl[1] = (uint4){l4, l5, l6, l7};
        } else {
#pragma unroll
            for (int s = t; s < BM * 4; s += 256) {
                int row = s >> 2, kc = s & 3;
                int gr = m0 + row; if (gr > ROWS - 1) gr = ROWS - 1;
                size_t gb = ((size_t)gr * K + kb) * 2 + kc * 16;
                int lb = (s & ~63) * 16;
                gl_lds16((const char*)Ahi + gb, (char*)sAh + lb);
                gl_lds16((const char*)Alo + gb, (char*)sAl + lb);
            }
        }
#pragma unroll
        for (int s = t; s < BN * 4; s += 256) {
            int row = s >> 2, kc = s & 3;
            size_t gb = ((size_t)(n0 + row) * K + kb) * 2 + kc * 16;
            int lb = (s & ~63) * 16;
            gl_lds16((const char*)Bhi + gb, (char*)sBh + lb);
            gl_lds16((const char*)Blo + gb, (char*)sBl + lb);
        }
        __syncthreads();

        // issue NEXT K-step's A loads AFTER the barrier (latency hides under
        // the MFMA phase; the pre-barrier vmcnt(0) drain doesn't catch them).
        if (MODE == 0 && kb + 32 < K) {
            const float* src = &Af[a_base + kb + 32];
            a0r = *(const float4*)&src[0];
            a1r = *(const float4*)&src[4];
            a2r = *(const float4*)&src[8];
            a3r = *(const float4*)&src[12];
        }

        short8 ah[MT], al[MT], bh[NT], bl[NT];
#pragma unroll
        for (int i = 0; i < MT; ++i) {
            int off = (wm * (BM / 2) + i * 16 + ln) * 32 + quad * 8;
            ah[i] = *(const short8*)&sAh[off];
            al[i] = *(const short8*)&sAl[off];
        }
#pragma unroll
        for (int j = 0; j < NT; ++j) {
            int off = (wn * (BN / 2) + j * 16 + ln) * 32 + quad * 8;
            bh[j] = *(const short8*)&sBh[off];
            bl[j] = *(const short8*)&sBl[off];
        }
#pragma unroll
        for (int i = 0; i < MT; ++i)
#pragma unroll
            for (int j = 0; j < NT; ++j) {
                acc[i][j] = __builtin_amdgcn_mfma_f32_16x16x32_bf16(ah[i], bh[j], acc[i][j], 0, 0, 0);
                acc[i][j] = __builtin_amdgcn_mfma_f32_16x16x32_bf16(ah[i], bl[j], acc[i][j], 0, 0, 0);
                acc[i][j] = __builtin_amdgcn_mfma_f32_16x16x32_bf16(al[i], bh[j], acc[i][j], 0, 0, 0);
            }
    }

#pragma unroll
    for (int i = 0; i < MT; ++i) {
#pragma unroll
        for (int r2 = 0; r2 < 4; ++r2) {
            int gm = m0 + wm * (BM / 2) + i * 16 + quad * 4 + r2;
            if (gm >= ROWS) continue;
            if (MODE == 0) {
                int jn = gm % 289;
                const float* Mrow = &aux[(size_t)jn * 256];
#pragma unroll
                for (int j = 0; j < NT; ++j) {
                    int gn = n0 + wn * (BN / 2) + j * 16 + ln;
                    out[(size_t)gm * 1280 + gn] = acc[i][j][r2] * Mrow[gn & 255];
                }
            } else {
#pragma unroll
                for (int j = 0; j < NT; ++j) {
                    int gn = n0 + wn * (BN / 2) + j * 16 + ln;
                    out[(size_t)gm * 256 + gn] = acc[i][j][r2] + aux[gn];
                }
            }
        }
    }
}

// ---------------- fused attention: scores + softmaxes + all combines -----
// 512 threads (8 waves) per (b,h), grid 512. LDS 69.4 KB, (512,4) = 64 VGPR
// cap -> 2 blocks/CU.
// Round-17 BISECTION: round-16's three sync edits raced post-timing (m152
// lesson — one sync change at a time). This kernel = round-15 barrier
// skeleton EXACTLY (P2 standalone after post-P1M barrier; P3.5 standalone
// with own barrier) + ONLY the provably-safe khalf1 fused load-or-zero
// (single writer per LDS location between barriers; round-15's bulk-zero +
// mid-barrier + restage had a WAW that the fused form eliminates).
__global__ __launch_bounds__(512, 4) void k_att(
    const float* __restrict__ qkv5,
    const float* __restrict__ A_s, const float* __restrict__ A_v,
    const float* __restrict__ adjS, const float* __restrict__ adjV,
    ushort_t* __restrict__ yhi, ushort_t* __restrict__ ylo)
{
    __shared__ __attribute__((aligned(16))) float sm[17340];
    float* aS  = sm;            // 4913  [n][j][k]
    float* aV  = sm + 4913;     // 4913  [j][n][m]
    float* ebS = sm + 9826;     // 289
    float* ebV = sm + 10115;    // 289
    float* buf = sm + 10404;    // P3: vsv_t hi/lo (5376) | P4/P5: 289*24

    const int t  = threadIdx.x;
    const int bh = blockIdx.x;
    const int b  = bh >> 3, h = bh & 7;
    const size_t rowbase = (size_t)b * 289;

    // ---- P0: exp of symmetrized biases ----
    for (int idx = t; idx < 578; idx += 512) {
        int f = idx / 289, rem = idx % 289;
        int jj = rem / 17, kk = rem % 17;
        float bias;
        if (f == 0)
            bias = 0.5f * ((A_s[jj*17+kk] + adjS[jj*17+kk]) + (A_s[kk*17+jj] + adjS[kk*17+jj]));
        else
            bias = 0.5f * ((A_v[jj*17+kk] + adjV[jj*17+kk]) + (A_v[kk*17+jj] + adjV[kk*17+jj]));
        (f ? ebV : ebS)[rem] = expf(bias);
    }

    // ---- P1M: raw scores via MFMA (diagonal 17x17 blocks of QK^T) ----
    {
        const int lane = t & 63;
        const int ln = lane & 15, quad = lane >> 4;
        const int wave = t >> 6;                   // 0..7
        const float* qb = &qkv5[rowbase * 1280 + h * 32];
        const float* kb = &qkv5[rowbase * 1280 + 256 + h * 32];

        // main 16x16 tiles: rows/cols 0..15 of each 17x17 block
        for (int g = wave; g < 34; g += 8) {
            const bool isV = (g < 17);
            const int gg = isV ? g : g - 17;
            const int rp = isV ? (gg * 17 + ln) : (ln * 17 + gg);
            const float* qsrc = &qb[(size_t)rp * 1280 + quad * 8];
            const float* ksrc = &kb[(size_t)rp * 1280 + quad * 8];
            float4 qv0 = *(const float4*)&qsrc[0];
            float4 qv1 = *(const float4*)&qsrc[4];
            float4 kv0 = *(const float4*)&ksrc[0];
            float4 kv1 = *(const float4*)&ksrc[4];
            union { short8 s; unsigned u[4]; } Ah, Al, Bh, Bl;
            Ah.u[0] = cvtpk(qv0.x, qv0.y); Ah.u[1] = cvtpk(qv0.z, qv0.w);
            Ah.u[2] = cvtpk(qv1.x, qv1.y); Ah.u[3] = cvtpk(qv1.z, qv1.w);
            Al.u[0] = cvtpk(qv0.x - uasf(Ah.u[0] << 16), qv0.y - uasf(Ah.u[0] & 0xffff0000u));
            Al.u[1] = cvtpk(qv0.z - uasf(Ah.u[1] << 16), qv0.w - uasf(Ah.u[1] & 0xffff0000u));
            Al.u[2] = cvtpk(qv1.x - uasf(Ah.u[2] << 16), qv1.y - uasf(Ah.u[2] & 0xffff0000u));
            Al.u[3] = cvtpk(qv1.z - uasf(Ah.u[3] << 16), qv1.w - uasf(Ah.u[3] & 0xffff0000u));
            Bh.u[0] = cvtpk(kv0.x, kv0.y); Bh.u[1] = cvtpk(kv0.z, kv0.w);
            Bh.u[2] = cvtpk(kv1.x, kv1.y); Bh.u[3] = cvtpk(kv1.z, kv1.w);
            Bl.u[0] = cvtpk(kv0.x - uasf(Bh.u[0] << 16), kv0.y - uasf(Bh.u[0] & 0xffff0000u));
            Bl.u[1] = cvtpk(kv0.z - uasf(Bh.u[1] << 16), kv0.w - uasf(Bh.u[1] & 0xffff0000u));
            Bl.u[2] = cvtpk(kv1.x - uasf(Bh.u[2] << 16), kv1.y - uasf(Bh.u[2] & 0xffff0000u));
            Bl.u[3] = cvtpk(kv1.z - uasf(Bh.u[3] << 16), kv1.w - uasf(Bh.u[3] & 0xffff0000u));
            f32x4 acc = (f32x4){0.f, 0.f, 0.f, 0.f};
            acc = __builtin_amdgcn_mfma_f32_16x16x32_bf16(Ah.s, Bh.s, acc, 0, 0, 0);
            acc = __builtin_amdgcn_mfma_f32_16x16x32_bf16(Ah.s, Bl.s, acc, 0, 0, 0);
            acc = __builtin_amdgcn_mfma_f32_16x16x32_bf16(Al.s, Bh.s, acc, 0, 0, 0);
            float* dst = (isV ? aV : aS) + gg * 289;
#pragma unroll
            for (int i = 0; i < 4; ++i) {
                int row = quad * 4 + i;           // 0..15
                dst[row * 17 + ln] = acc[i];      // col = ln (0..15)
            }
        }

        // edges: entries with row==16 or col==16 (33 per block), f32 dots
        for (int e = t; e < 1122; e += 512) {
            int g = e / 33, s = e % 33;
            const bool isV = (g < 17);
            const int gg = isV ? g : g - 17;
            int rr = (s < 17) ? 16 : (s - 17);
            int cc = (s < 17) ? s : 16;
            int qp2 = isV ? (gg * 17 + rr) : (rr * 17 + gg);
            int kp2 = isV ? (gg * 17 + cc) : (cc * 17 + gg);
            const float* qsrc = &qb[(size_t)qp2 * 1280];
            const float* ksrc = &kb[(size_t)kp2 * 1280];
            float acc = 0.f;
#pragma unroll
            for (int c8 = 0; c8 < 8; ++c8) {
                float4 qv = *(const float4*)&qsrc[c8 * 4];
                float4 kv = *(const float4*)&ksrc[c8 * 4];
                acc += dot4(qv, kv);
            }
            (isV ? aV : aS)[gg * 289 + rr * 17 + cc] = acc;
        }
    }
    __syncthreads();

    // ---- P2: in-place 3-pass softmax on all 578 rows (SCALE folded) ----
    for (int idx = t; idx < 578; idx += 512) {
        float* row = (idx < 289) ? &aS[idx * 17] : &aV[(idx - 289) * 17];
        float mx = row[0];
#pragma unroll
        for (int kk = 1; kk < 17; ++kk) mx = fmaxf(mx, row[kk]);
        float sum = 0.f;
#pragma unroll
        for (int kk = 0; kk < 17; ++kk) {
            float e = expf((row[kk] - mx) * SCALE);
            row[kk] = e; sum += e;
        }
        float inv = 1.f / sum;
#pragma unroll
        for (int kk = 0; kk < 17; ++kk) row[kk] *= inv;
    }
    // (no trailing sync: P3's staging sync orders P2 before consumers)

    // ---- P3: x_vsv via in-register-A split-bf16 MFMA ----
    {
        const int lane = t & 63;
        const int ln = lane & 15, quad = lane >> 4;
        const int wave = t >> 6;                  // 0..7
        ushort_t* vh = (ushort_t*)buf;            // [32][168] bf16 hi (pad 168)
        ushort_t* vl = vh + 32 * 168;             // lo

        f32x4 acc[3][2];
#pragma unroll
        for (int r = 0; r < 3; ++r) {
            acc[r][0] = (f32x4){0.f,0.f,0.f,0.f};
            acc[r][1] = (f32x4){0.f,0.f,0.f,0.f};
        }

        // per-lane row bases for the (up to) 3 row-tiles this wave owns
        int sbase[3], vbase[3];
#pragma unroll
        for (int r = 0; r < 3; ++r) {
            int p = (wave + 8 * r) * 16 + ln; if (p > 288) p = 288;
            int jj = (p * 61681) >> 20;           // p / 17
            int nn = p - jj * 17;
            sbase[r] = nn * 289 + jj * 17;        // aS row (n,j)
            vbase[r] = jj * 289 + nn * 17;        // aV row (j,n)
        }

        for (int khalf = 0; khalf < 2; ++khalf) {
            const int qbase = khalf * 160;
            __syncthreads();
            if (khalf == 0) {
                // stage cols 0..159 (cols 160..167 never read in khalf0)
                for (int e = t; e < 32 * 160; e += 512) {
                    int ql = e >> 5, c = e & 31;
                    float v = qkv5[(rowbase + ql) * 1280 + 1024 + h * 32 + c];
                    unsigned hp = cvtpk(v, v);
                    float lo = v - uasf(hp << 16);
                    unsigned lp = cvtpk(lo, lo);
                    vh[c * 168 + ql] = (ushort_t)hp;
                    vl[c * 168 + ql] = (ushort_t)lp;
                }
            } else {
                // fused load-or-zero: each (c,ql) written exactly once
                // (ql<129: staged value; else 0). Single-writer => no WAW,
                // no mid-barrier (round-15's bulk-zero + barrier removed).
                for (int e = t; e < 32 * 168; e += 512) {
                    int ql = e >> 5, c = e & 31;
                    ushort_t hv = 0, lv = 0;
                    if (ql < 129) {
                        float v = qkv5[(rowbase + 160 + ql) * 1280 + 1024 + h * 32 + c];
                        unsigned hp = cvtpk(v, v);
                        float lo = v - uasf(hp << 16);
                        unsigned lp = cvtpk(lo, lo);
                        hv = (ushort_t)hp; lv = (ushort_t)lp;
                    }
                    vh[c * 168 + ql] = hv;
                    vl[c * 168 + ql] = lv;
                }
            }
            __syncthreads();
#pragma unroll
            for (int kstep = 0; kstep < 5; ++kstep) {
                const int q0 = qbase + kstep * 32 + quad * 8;
                const int lb = kstep * 32 + quad * 8;
#pragma unroll
                for (int r = 0; r < 3; ++r) {
                    if (r == 2 && wave >= 3) continue;   // rt>=19: no output
                    union { short8 s; unsigned u[4]; } A, L;
                    int qc0 = (q0 < 289) ? q0 : 288;     // clamp: in-bounds decode
                    int k17 = (qc0 * 61681) >> 20;       // qc0 / 17
                    int m17 = qc0 - k17 * 17;
                    float sv = aS[sbase[r] + k17];
#pragma unroll
                    for (int i2 = 0; i2 < 4; ++i2) {
                        float pv0 = sv * aV[vbase[r] + m17];
                        ++m17; if (m17 == 17) { m17 = 0; ++k17; sv = aS[sbase[r] + k17]; }
                        float pv1 = sv * aV[vbase[r] + m17];
                        ++m17; if (m17 == 17) { m17 = 0; ++k17; sv = aS[sbase[r] + k17]; }
                        if (khalf == 1) {                // khalf0: q <= 159 always valid
                            if (q0 + 2 * i2     >= 289) pv0 = 0.f;
                            if (q0 + 2 * i2 + 1 >= 289) pv1 = 0.f;
                        }
                        unsigned hp = cvtpk(pv0, pv1);
                        unsigned lp = cvtpk(pv0 - uasf(hp << 16),
                                            pv1 - uasf(hp & 0xffff0000u));
                        A.u[i2] = hp; L.u[i2] = lp;
                    }
#pragma unroll
                    for (int ct = 0; ct < 2; ++ct) {
                        short8 bh8 = *(const short8*)&vh[(ct * 16 + ln) * 168 + lb];
                        short8 bl8 = *(const short8*)&vl[(ct * 16 + ln) * 168 + lb];
                        acc[r][ct] = __builtin_amdgcn_mfma_f32_16x16x32_bf16(A.s, bh8, acc[r][ct], 0, 0, 0);
                        acc[r][ct] = __builtin_amdgcn_mfma_f32_16x16x32_bf16(A.s, bl8, acc[r][ct], 0, 0, 0);
                        acc[r][ct] = __builtin_amdgcn_mfma_f32_16x16x32_bf16(L.s, bh8, acc[r][ct], 0, 0, 0);
                    }
                }
            }
        }
        // store: D row = rt*16 + quad*4 + rr, col = ct*16 + ln
#pragma unroll
        for (int r = 0; r < 3; ++r) {
            int rt = wave + 8 * r;
            if (rt >= 19) continue;
#pragma unroll
            for (int ct = 0; ct < 2; ++ct) {
#pragma unroll
                for (int rr = 0; rr < 4; ++rr) {
                    int p = rt * 16 + quad * 4 + rr;
                    if (p > 288) continue;
                    float v = acc[r][ct][rr];
                    unsigned hp = cvtpk(v, v);
                    float lo = v - uasf(hp << 16);
                    unsigned lp = cvtpk(lo, lo);
                    size_t off = (rowbase + p) * 768 + h * 32 + ct * 16 + ln;
                    yhi[off] = (ushort_t)hp;
                    ylo[off] = (ushort_t)lp;
                }
            }
        }
    }

    // ---- P3.5: bias-normalize aS/aV IN PLACE (P3 was the last unbiased
    // consumer). row = row*eb / sum(row*eb). Barrier first: other waves may
    // still be reading unbiased values inside P3.
    __syncthreads();
    for (int idx = t; idx < 578; idx += 512) {
        float* row;
        const float* eb;
        if (idx < 289) { row = &aS[idx * 17]; eb = &ebS[(idx % 17) * 17]; }
        else { int i2 = idx - 289; row = &aV[i2 * 17]; eb = &ebV[(i2 % 17) * 17]; }
        float s = 0.f;
#pragma unroll
        for (int kk = 0; kk < 17; ++kk) { float wv = row[kk] * eb[kk]; row[kk] = wv; s += wv; }
        float inv = 1.f / s;
#pragma unroll
        for (int kk = 0; kk < 17; ++kk) row[kk] *= inv;
    }

    // ---- P4: x_vs -> y cols 256..511. c4-fastest map, buf stride 24 ----
    for (int ch = 0; ch < 2; ++ch) {
        __syncthreads();
        for (int idx = t; idx < 1156; idx += 512) {
            int p = idx >> 2, c = idx & 3;
            *(float4*)&buf[p * 24 + c * 4] =
                *(const float4*)&qkv5[(rowbase + p) * 1280 + 512 + h * 32 + ch * 16 + c * 4];
        }
        __syncthreads();
        for (int u = t; u < 1156; u += 512) {
            const int c4 = (u & 3) * 4, rest = u >> 2;   // rest 0..288
            const int n = rest % 17, j = rest / 17;
            const float* as = &aS[n * 289 + j * 17];     // pre-normalized biased
            float4 a0 = {0,0,0,0};
            for (int kk = 0; kk < 17; ++kk) {
                float4 v = *(const float4*)&buf[(kk * 17 + n) * 24 + c4];
                fma4(a0, as[kk], v);
            }
            store_hilo(yhi, ylo, (rowbase + j * 17 + n) * 768 + 256 + h * 32 + ch * 16 + c4, a0);
        }
    }

    // ---- P5: x_vv -> y cols 512..767. c4-fastest map, buf stride 24 ----
    for (int ch = 0; ch < 2; ++ch) {
        __syncthreads();
        for (int idx = t; idx < 1156; idx += 512) {
            int p = idx >> 2, c = idx & 3;
            *(float4*)&buf[p * 24 + c * 4] =
                *(const float4*)&qkv5[(rowbase + p) * 1280 + 768 + h * 32 + ch * 16 + c * 4];
        }
        __syncthreads();
        for (int u = t; u < 1156; u += 512) {
            const int c4 = (u & 3) * 4, rest = u >> 2;   // rest 0..288
            const int j = rest % 17, n = rest / 17;
            const float* av = &aV[j * 289 + n * 17];     // pre-normalized biased
            float4 a0 = {0,0,0,0};
            for (int mm = 0; mm < 17; ++mm) {
                float4 v = *(const float4*)&buf[(j * 17 + mm) * 24 + c4];
                fma4(a0, av[mm], v);
            }
            store_hilo(yhi, ylo, (rowbase + j * 17 + n) * 768 + 512 + h * 32 + ch * 16 + c4, a0);
        }
    }
}

extern "C" void kernel_launch(void* const* d_in, const int* in_sizes, int n_in,
                              void* d_out, int out_size, void* d_ws, size_t ws_size,
                              hipStream_t stream)
{
    const float* x    = (const float*)d_in[0];
    const float* A_s  = (const float*)d_in[1];
    const float* A_v  = (const float*)d_in[2];
    const float* Wqkv = (const float*)d_in[3];
    const float* Wp   = (const float*)d_in[4];
    const float* bp   = (const float*)d_in[5];
    const float* M    = (const float*)d_in[6];
    const float* adjS = (const float*)d_in[7];
    const float* adjV = (const float*)d_in[8];
    float* out = (float*)d_out;

    char* w = (char*)d_ws;
    float*    qkv5  = (float*)w;                          // 94.7 MB, dead after k_att
    ushort_t* wph   = (ushort_t*)(w + 94699520);          // dead gap after qkv5
    ushort_t* wpl   = (ushort_t*)(w + 94699520 + 393216);
    char* R = w + 134946816;
    ushort_t* wqh = (ushort_t*)(R + 18939904);
    ushort_t* wql = (ushort_t*)(R + 19595264);
    ushort_t* yhi = (ushort_t*)R;
    ushort_t* ylo = (ushort_t*)(R + 28422144);

    k_cvt_w<<<dim3(1536), 256, 0, stream>>>(Wqkv, wqh, wql, Wp, wph, wpl);
    k_gemm<128, 128, 256, 0><<<dim3(10, 145), 256, 0, stream>>>(x, nullptr, nullptr,
                                                                wqh, wql, M, qkv5);
    k_att<<<dim3(512), 512, 0, stream>>>(qkv5, A_s, A_v, adjS, adjV, yhi, ylo);
    k_gemm<128, 64, 768, 1><<<dim3(4, 145), 256, 0, stream>>>(nullptr, yhi, ylo,
                                                              wph, wpl, bp, out);
}